// Round 13
// baseline (35.254 us; speedup 1.0000x reference)
//
#include <hip/hip_runtime.h>

#define BB 256
#define SS 2048
#define FF 64
#define NBB 32

#define TPB 512            // 8 waves: 6 producer + 2 consumer
#define PT 384             // producer threads
#define CT 128             // consumer threads
#define MT 4               // outputs per consumer thread
#define OTS 512            // outputs per sub-chunk
#define NSC 2              // sub-chunks per block
#define OT (OTS*NSC)       // 1024 outputs per block
#define WUP 32             // speculative warm-up (validated r12, absmax at floor)
#define ROWS (OTS+WUP)     // 544 u rows per sub-chunk
#define NGRP (PT/16)       // 24 16-lane producer groups
#define RPG ((ROWS+NGRP-1)/NGRP)  // 23 rows per group
#define NF2 (ROWS/2)       // 272 float2 per u buffer
#define NCHUNK (SS/OT)     // 2 halves of the sequence

// 2*log2(e): folded into u so the chain needs only exp2
#define TWO_OVER_LN2 2.885390081777927f

// ---------------------------------------------------------------------------
// ONE kernel, producer/consumer waves INSIDE each block (round-3's idea done
// right: sync is block-local __syncthreads + LDS double-buffer, NOT cross-XCD
// atomics). block = (batch b, half of t). Pipeline:
//   proj(0) -> sync -> { proj(1) || cons(0) } -> sync -> cons(1)
// so the trans-bound chain+head overlaps the next sub-chunk's HBM loads via
// wave-level co-scheduling (m114). Fetch unchanged vs r12 (6.25% warm-up dup).
//  producer waves (0-5): 16-lane-group dot(X,W_ih) -> u,tf into LDS buf c&1.
//  consumer waves (6-7): thread j: 32-step speculative chain (LDS float2,
//    4-deep static rotating prefetch) -> 4 output steps -> 32-basis head ->
//    8 dword stores. Exact hx0 start for the t<WUP window (cndmask on chain).
// XCD swizzle: 32 consecutive b per XCD so [t][b] output lines aggregate in
// one XCD's L2.
// ---------------------------------------------------------------------------

#define CSTEP_P(uu, kk) { \
    float z_ = fmaf(m2w, r, (uu)); \
    float rn_ = __builtin_amdgcn_rcpf(__builtin_amdgcn_exp2f(z_) + 1.0f); \
    r = ((kk) >= K0) ? rn_ : r; }

#define CSTEP_N(uu, kk) { \
    float z_ = fmaf(m2w, r, (uu)); \
    r = __builtin_amdgcn_rcpf(__builtin_amdgcn_exp2f(z_) + 1.0f); }

#define OSTEP(uu, kk) { \
    float z_ = fmaf(m2w, r, (uu)); \
    r = __builtin_amdgcn_rcpf(__builtin_amdgcn_exp2f(z_) + 1.0f); \
    hxr[kk] = fmaf(-2.0f, r, 1.0f); }

// 4 groups x 8 steps; each float2 pfX used then refilled 8 steps ahead
// (~240cy chain > ~120cy LDS latency). All buffer indexing static. After the
// last group pf0,pf1 = rows j*4+32..35 = this thread's 4 output u values.
#define WARMLOOP(CS) \
    _Pragma("unroll 1") \
    for (int grp = 0; grp < WUP/8; ++grp) { \
        const int kb = grp * 8; \
        const int rb = jb + grp*4 + 4; \
        { const float2 c_ = pf0; CS(c_.x, kb+0) CS(c_.y, kb+1) \
          int ri_ = rb+0; if (ri_ > NF2-1) ri_ = NF2-1; pf0 = U2[ri_]; } \
        { const float2 c_ = pf1; CS(c_.x, kb+2) CS(c_.y, kb+3) \
          int ri_ = rb+1; if (ri_ > NF2-1) ri_ = NF2-1; pf1 = U2[ri_]; } \
        { const float2 c_ = pf2; CS(c_.x, kb+4) CS(c_.y, kb+5) \
          int ri_ = rb+2; if (ri_ > NF2-1) ri_ = NF2-1; pf2 = U2[ri_]; } \
        { const float2 c_ = pf3; CS(c_.x, kb+6) CS(c_.y, kb+7) \
          int ri_ = rb+3; if (ri_ > NF2-1) ri_ = NF2-1; pf3 = U2[ri_]; } \
    }

__global__ __launch_bounds__(TPB) void k_one(
    const float* __restrict__ X, const float* __restrict__ hx0,
    const float* __restrict__ W_ih, const float* __restrict__ b_ih,
    const float* __restrict__ W_hh, const float* __restrict__ b_hh,
    const float* __restrict__ W_h2p, const float* __restrict__ b_h2p,
    float* __restrict__ out_h, float* __restrict__ out_l)
{
    __shared__ __align__(16) float u_lds[2][ROWS];
    __shared__ __align__(16) float tf_lds[2][OTS];
    __shared__ float4 cb[NBB];

    // block decode with XCD swizzle: b in [xcd*32, xcd*32+32), 2 halves each
    const int bid  = blockIdx.x;
    const int xcd  = bid & 7;
    const int qq   = bid >> 3;               // 0..63
    const int b    = xcd * 32 + (qq & 31);
    const int half = qq >> 5;                // 0..1
    const int TH0  = half * OT;

    if (threadIdx.x < NBB) {
        int jj = threadIdx.x;
        cb[jj] = make_float4(W_h2p[2*jj], W_h2p[2*jj+1], b_h2p[2*jj], b_h2p[2*jj+1]);
    }

    const float wp  = W_hh[0] * TWO_OVER_LN2;
    const float m2w = -2.0f * wp;
    const float h0  = hx0[b];

    // producer locals (computed by all threads; used by producer path)
    const int l = threadIdx.x & 15;
    const int g = threadIdx.x >> 4;          // 0..23 valid for producers
    const float4 w = reinterpret_cast<const float4*>(W_ih)[l];
    const float bias = b_ih[0] + b_hh[0];
    const float* Xb = X + (size_t)b * SS * FF;

    auto PROJ = [&](int c, int bufi) {
        const int Tc = TH0 + c * OTS - WUP;  // global t of LDS row 0
        #pragma unroll 4
        for (int it = 0; it < RPG; ++it) {   // 23 iters
            const int i = g + it * NGRP;     // LDS row (group-uniform)
            const int t = Tc + i;
            float pacc = 0.0f, vy = 0.0f;
            if (i < ROWS && t >= 0) {        // group-uniform predicates
                const float4 v = reinterpret_cast<const float4*>(
                    Xb + (size_t)t * FF)[l];
                pacc = v.x*w.x + v.y*w.y + v.z*w.z + v.w*w.w;
                vy = v.y;
            }
            pacc += __shfl_xor(pacc, 1);
            pacc += __shfl_xor(pacc, 2);
            pacc += __shfl_xor(pacc, 4);
            pacc += __shfl_xor(pacc, 8);
            if (l == 0 && i < ROWS) {
                u_lds[bufi][i] = (t >= 0) ? (TWO_OVER_LN2 * (pacc + bias) + wp)
                                          : 0.0f;
                if (i >= WUP) tf_lds[bufi][i - WUP] = vy;   // X[b,t,1]
            }
        }
    };

    auto CONS = [&](int c, int bufi) {
        const int j   = threadIdx.x - PT;    // 0..127
        const int t0l = j * MT;              // local output t, [0,512)
        const int T0c = TH0 + c * OTS;
        float r; int K0;
        if (T0c == 0 && t0l < WUP) { r = 0.5f * (1.0f - h0); K0 = WUP - t0l; }
        else                        { r = 0.5f;              K0 = 0; }
        const float2* U2 = reinterpret_cast<const float2*>(u_lds[bufi]);
        const int jb = j * 2;
        float2 pf0 = U2[jb], pf1 = U2[jb+1], pf2 = U2[jb+2], pf3 = U2[jb+3];

        if (T0c == 0) { WARMLOOP(CSTEP_P) }  // block-uniform branch
        else          { WARMLOOP(CSTEP_N) }

        float hxr[MT];
        OSTEP(pf0.x, 0) OSTEP(pf0.y, 1) OSTEP(pf1.x, 2) OSTEP(pf1.y, 3)

        // ---------------- intensity head, in-register ----------------
        const float4 ttv = reinterpret_cast<const float4*>(tf_lds[bufi])[j];
        const float tt[MT] = { ttv.x, ttv.y, ttv.z, ttv.w };
        float s[MT] = { 0.0f, 0.0f, 0.0f, 0.0f };
        #pragma unroll 8
        for (int jj = 0; jj < NBB; ++jj) {
            const float4 cc = cb[jj];        // uniform LDS broadcast
            #pragma unroll
            for (int k = 0; k < MT; ++k)
                s[k] += fmaxf(fmaf(fmaf(hxr[k], cc.x, cc.z), tt[k],
                                   fmaf(hxr[k], cc.y, cc.w)), 0.0f);
        }
        const size_t o0 = (size_t)(T0c + t0l) * BB + b;
        #pragma unroll
        for (int k = 0; k < MT; ++k) {
            out_h[o0 + (size_t)k * BB] = hxr[k];
            float vv = s[k];
            float as = fabsf(vv);
            float e  = __builtin_amdgcn_exp2f(-as * 1.4426950408889634f);
            float lg = __builtin_amdgcn_logf(1.0f + e) * 0.6931471805599453f;
            out_l[o0 + (size_t)k * BB] = fmaxf(vv, 0.0f) + lg;
        }
    };

    const bool is_prod = (threadIdx.x < PT);   // wave-aligned split (6P/2C)

    if (is_prod) PROJ(0, 0);
    __syncthreads();
    if (is_prod) PROJ(1, 1); else CONS(0, 0);
    __syncthreads();
    if (!is_prod) CONS(1, 1);
}

// ---------------------------------------------------------------------------
extern "C" void kernel_launch(void* const* d_in, const int* in_sizes, int n_in,
                              void* d_out, int out_size, void* d_ws, size_t ws_size,
                              hipStream_t stream) {
    const float* X     = (const float*)d_in[0];
    const float* hx0   = (const float*)d_in[1];
    const float* W_ih  = (const float*)d_in[2];
    const float* b_ih  = (const float*)d_in[3];
    const float* W_hh  = (const float*)d_in[4];
    const float* b_hh  = (const float*)d_in[5];
    const float* W_h2p = (const float*)d_in[6];
    const float* b_h2p = (const float*)d_in[7];

    float* out_h = (float*)d_out;                 // hidden_states (S,B,1) [t][b]
    float* out_l = out_h + (size_t)SS * BB;       // intensity     (S,B)   [t][b]

    k_one<<<NCHUNK * BB, TPB, 0, stream>>>(X, hx0, W_ih, b_ih, W_hh, b_hh,
                                           W_h2p, b_h2p, out_h, out_l);
}

// Round 14
// 31.271 us; speedup vs baseline: 1.1274x; 1.1274x over previous
//
#include <hip/hip_runtime.h>

#define BB 256
#define SS 2048
#define FF 64
#define NBB 32

#define TPB 256            // threads per block (4 waves)
#define MT 2               // output timesteps per thread
#define OT (TPB*MT)        // 512 output t per block
#define WUP 32             // speculative warm-up steps (validated r12)
#define ROWS (OT+WUP)      // 544 u rows in LDS
#define NCHUNK (SS/OT)     // 4 t-chunks
#define NGRP (TPB/16)      // 16 16-lane groups
#define RPG (ROWS/NGRP)    // 34 rows per group (exact)
#define NF2 (ROWS/2)       // 272 float2 in u_lds

// 2*log2(e): folded into u so the chain needs only exp2
#define TWO_OVER_LN2 2.885390081777927f

// ---------------------------------------------------------------------------
// r12 structure (best: 31.17us) with ONE isolated change in phase 1:
// the 16-lane dot-reduce uses DPP row_ror rotate-adds (VALU pipe) instead of
// 4x ds_swizzle shfl_xor (LDS pipe, 4-deep serial ~40-120cy each). This is
// the discriminating experiment for the remaining 7us over the BW floor:
// if DS latency/issue was the residue -> ~29-30us; if unchanged -> phase 1
// is at the effective BW ceiling and the structure is roofline.
// ---------------------------------------------------------------------------

// rotate-within-16-lane-row and add: pure VALU (v_mov_b32_dpp + v_add_f32)
#define ROR_ADD(x, N) { \
    float y_ = __int_as_float(__builtin_amdgcn_update_dpp( \
        0, __float_as_int(x), 0x120 + (N), 0xF, 0xF, false)); \
    x += y_; }

#define CSTEP_P(uu, kk) { \
    float z_ = fmaf(m2w, r, (uu)); \
    float rn_ = __builtin_amdgcn_rcpf(__builtin_amdgcn_exp2f(z_) + 1.0f); \
    r = ((kk) >= K0) ? rn_ : r; }

#define CSTEP_N(uu, kk) { \
    float z_ = fmaf(m2w, r, (uu)); \
    r = __builtin_amdgcn_rcpf(__builtin_amdgcn_exp2f(z_) + 1.0f); }

// 4 groups x 8 steps; each float2 pfX used then refilled 8 steps ahead
// (~240cy of chain > ~120cy LDS latency). All buffer indexing static.
// After the last group, pf0 = U2[j+WUP/2] = this thread's 2 output u values.
#define WARMLOOP(CS) \
    _Pragma("unroll 1") \
    for (int grp = 0; grp < WUP/8; ++grp) { \
        const int kb = grp * 8; \
        const int rb = j + grp*4 + 4; \
        { const float2 c_ = pf0; CS(c_.x, kb+0) CS(c_.y, kb+1) \
          int ri_ = rb + 0; if (ri_ > NF2-1) ri_ = NF2-1; pf0 = U2[ri_]; } \
        { const float2 c_ = pf1; CS(c_.x, kb+2) CS(c_.y, kb+3) \
          int ri_ = rb + 1; if (ri_ > NF2-1) ri_ = NF2-1; pf1 = U2[ri_]; } \
        { const float2 c_ = pf2; CS(c_.x, kb+4) CS(c_.y, kb+5) \
          int ri_ = rb + 2; if (ri_ > NF2-1) ri_ = NF2-1; pf2 = U2[ri_]; } \
        { const float2 c_ = pf3; CS(c_.x, kb+6) CS(c_.y, kb+7) \
          int ri_ = rb + 3; if (ri_ > NF2-1) ri_ = NF2-1; pf3 = U2[ri_]; } \
    }

__global__ __launch_bounds__(TPB) void k_one(
    const float* __restrict__ X, const float* __restrict__ hx0,
    const float* __restrict__ W_ih, const float* __restrict__ b_ih,
    const float* __restrict__ W_hh, const float* __restrict__ b_hh,
    const float* __restrict__ W_h2p, const float* __restrict__ b_h2p,
    float* __restrict__ out_h, float* __restrict__ out_l)
{
    __shared__ __align__(16) float u_lds[ROWS];
    __shared__ __align__(16) float tf_lds[OT];
    __shared__ float4 cb[NBB];

    // block decode with XCD swizzle: b in [xcd*32, xcd*32+32), 4 chunks each
    const int bid   = blockIdx.x;
    const int xcd   = bid & 7;
    const int qq    = bid >> 3;              // 0..127
    const int b     = xcd * 32 + (qq & 31);
    const int chunk = qq >> 5;               // 0..3
    const int T0    = chunk * OT;

    if (threadIdx.x < NBB) {
        int jj = threadIdx.x;
        cb[jj] = make_float4(W_h2p[2*jj], W_h2p[2*jj+1], b_h2p[2*jj], b_h2p[2*jj+1]);
    }

    const float wp  = W_hh[0] * TWO_OVER_LN2;
    const float m2w = -2.0f * wp;

    // ---------------- phase 1: projection into LDS ----------------
    {
        const int l = threadIdx.x & 15;
        const int g = threadIdx.x >> 4;              // 0..15
        const float4 w = reinterpret_cast<const float4*>(W_ih)[l];
        const float bias = b_ih[0] + b_hh[0];
        const float* Xb = X + (size_t)b * SS * FF;
        #pragma unroll 8
        for (int it = 0; it < RPG; ++it) {           // 34 iters
            const int i = g + it * NGRP;             // LDS row
            const int t = T0 - WUP + i;              // global timestep
            float pacc = 0.0f, vy = 0.0f;
            if (t >= 0) {                            // group-uniform predicate
                const float4 v = reinterpret_cast<const float4*>(
                    Xb + (size_t)t * FF)[l];
                pacc = v.x*w.x + v.y*w.y + v.z*w.z + v.w*w.w;
                vy = v.y;
            }
            ROR_ADD(pacc, 8)
            ROR_ADD(pacc, 4)
            ROR_ADD(pacc, 2)
            ROR_ADD(pacc, 1)
            if (l == 0) {
                u_lds[i] = (t >= 0) ? (TWO_OVER_LN2 * (pacc + bias) + wp) : 0.0f;
                if (i >= WUP) tf_lds[i - WUP] = vy;  // X[b,t,1]
            }
        }
    }
    __syncthreads();

    // ---------------- phase 2: private speculative chain ----------------
    const int j  = threadIdx.x;
    const int t0 = j * MT;                           // local output t (even)

    float r; int K0;
    if (chunk == 0 && t0 < WUP) { r = 0.5f * (1.0f - hx0[b]); K0 = WUP - t0; }
    else                        { r = 0.5f;          K0 = 0; }

    const float2* U2 = reinterpret_cast<const float2*>(u_lds);
    float2 pf0 = U2[j], pf1 = U2[j+1], pf2 = U2[j+2], pf3 = U2[j+3];

    if (chunk == 0) { WARMLOOP(CSTEP_P) }            // uniform branch per block
    else            { WARMLOOP(CSTEP_N) }

    // after the loop pf0 = u[t0+WUP], u[t0+WUP+1] — the two output steps
    float hxa, hxb;
    { float z = fmaf(m2w, r, pf0.x);
      r = __builtin_amdgcn_rcpf(__builtin_amdgcn_exp2f(z) + 1.0f);
      hxa = fmaf(-2.0f, r, 1.0f); }
    { float z = fmaf(m2w, r, pf0.y);
      r = __builtin_amdgcn_rcpf(__builtin_amdgcn_exp2f(z) + 1.0f);
      hxb = fmaf(-2.0f, r, 1.0f); }

    // ---------------- intensity head, in-register ----------------
    const float2 ttv = reinterpret_cast<const float2*>(tf_lds)[j];
    float s0 = 0.0f, s1 = 0.0f;
    #pragma unroll 8
    for (int jj = 0; jj < NBB; ++jj) {
        const float4 c = cb[jj];                     // uniform LDS broadcast
        s0 += fmaxf(fmaf(fmaf(hxa, c.x, c.z), ttv.x, fmaf(hxa, c.y, c.w)), 0.0f);
        s1 += fmaxf(fmaf(fmaf(hxb, c.x, c.z), ttv.y, fmaf(hxb, c.y, c.w)), 0.0f);
    }

    const size_t o0 = (size_t)(T0 + t0) * BB + b;
    out_h[o0]      = hxa;
    out_h[o0 + BB] = hxb;
    { float as = fabsf(s0);
      float e  = __builtin_amdgcn_exp2f(-as * 1.4426950408889634f);
      float lg = __builtin_amdgcn_logf(1.0f + e) * 0.6931471805599453f;
      out_l[o0] = fmaxf(s0, 0.0f) + lg; }
    { float as = fabsf(s1);
      float e  = __builtin_amdgcn_exp2f(-as * 1.4426950408889634f);
      float lg = __builtin_amdgcn_logf(1.0f + e) * 0.6931471805599453f;
      out_l[o0 + BB] = fmaxf(s1, 0.0f) + lg; }
}

// ---------------------------------------------------------------------------
extern "C" void kernel_launch(void* const* d_in, const int* in_sizes, int n_in,
                              void* d_out, int out_size, void* d_ws, size_t ws_size,
                              hipStream_t stream) {
    const float* X     = (const float*)d_in[0];
    const float* hx0   = (const float*)d_in[1];
    const float* W_ih  = (const float*)d_in[2];
    const float* b_ih  = (const float*)d_in[3];
    const float* W_hh  = (const float*)d_in[4];
    const float* b_hh  = (const float*)d_in[5];
    const float* W_h2p = (const float*)d_in[6];
    const float* b_h2p = (const float*)d_in[7];

    float* out_h = (float*)d_out;                 // hidden_states (S,B,1) [t][b]
    float* out_l = out_h + (size_t)SS * BB;       // intensity     (S,B)   [t][b]

    k_one<<<NCHUNK * BB, TPB, 0, stream>>>(X, hx0, W_ih, b_ih, W_hh, b_hh,
                                           W_h2p, b_h2p, out_h, out_l);
}